// Round 11
// baseline (243.724 us; speedup 1.0000x reference)
//
#include <hip/hip_runtime.h>
#include <math.h>

// Problem constants: y is (8, 3, 256, 512) fp32, lmbd is (1,3).
#define TVW 512      // row length
#define TVH 256      // H (for channel index)
#define TVC 3        // channels
#define WPB 2        // waves (= rows) per block; 3072 blocks -> 12 blk/CU, 24 waves/CU
#define BLOCK (WPB * 64)
#define PADF 128     // pad floats: max window read = 511+56+63 = 630 row-rel < 512+128

// v13 = v12 with the LDS pipe starved. r10 falsified SALU-bound (offload
// moved VALUBusy 53->60 with zero wall change). Recount: VALU-busy implies
// ~2500 absorbs/row (rescan factor ~5); at 1.5 wave-uniform ds_reads/absorb
// x 24 waves/CU, the per-CU-shared LDS pipe demand ~= the entire wall.
// Fix: broadcast via registers, not LDS:
//  - y-window: ONE per-lane ds_read loads 64 consecutive elements into a
//    VGPR; each step extracts with v_readlane (VALU->SGPR). LDS ops/absorb
//    1.5 -> ~0.03. Double-buffered, stride-56 slides, ~50-step slack.
//  - bneg gone: sign applied per-step via u_t = fma(sgn,y,u)-v (bitwise =
//    old add with pre-negated copy).
//  - rtab gone: reciprocal window rwin[lane]=rcp(lane+1+56s) (v8 precedent:
//    rcp <=1ulp passed); windows 0/1 are per-wave constants.
//  - handlers reload both windows (2 per-lane reads/event); nv =
//    readlane(ywin,0); restart algebra sign-folded into fmas (checked
//    case-by-case vs v12). No shared tables -> NO __syncthreads at all.
__global__ __launch_bounds__(BLOCK)
void tv1d_condat_wave_kernel(const float* __restrict__ y,
                             const float* __restrict__ lmbd,
                             float* __restrict__ out,
                             int total_rows) {
    __shared__ __align__(16) float buf[WPB * TVW + PADF];
    const int tid  = threadIdx.x;
    const int wave = tid >> 6;
    const int lane = tid & 63;
    const int l32  = lane & 31;
    const bool hi  = lane >= 32;
    const int row  = blockIdx.x * WPB + wave;

// uniform float extract: v_readlane (lane index SGPR or inline const)
#define RLF(SRC, IDX) __uint_as_float(__builtin_amdgcn_readlane(__float_as_uint(SRC), (IDX)))

    if (row < total_rows) {
        // ---- per-wave staging: own row only (coalesced float4) ----
        {
            const float4* s4 = (const float4*)(y + (size_t)row * TVW);
            float4* b4 = (float4*)(buf + wave * TVW);
            #pragma unroll
            for (int i = 0; i < TVW / 4; i += 64)
                b4[i + lane] = s4[i + lane];
        }

        const int c = (row / TVH) % TVC;
        float lam = log1pf(expf(lmbd[c]));   // softplus, once per row
        lam = __uint_as_float(__builtin_amdgcn_readfirstlane(__float_as_uint(lam)));
        const float nlam   = -lam;
        const float twolam = 2.0f * lam;
        float* x = buf + wave * TVW;         // row; prefix [..k0) never re-read

        const float sgn   = hi ? -1.0f : 1.0f;     // hi runs the mirrored walk
        const float vnlam = -lam;                  // fma addend (VGPR-friendly)
        const float vmcn  = hi ? -twolam : -0.0f;  // -(cneg): neg-jump restart
        const float vmcp  = hi ? -0.0f : -twolam;  // -(cpos): pos-jump restart
        const float laneF = (float)lane;
        const float rw0c  = __builtin_amdgcn_rcpf(laneF + 1.0f);   // den window 0
        const float rw1c  = __builtin_amdgcn_rcpf(laneF + 57.0f);  // den window 1

        // All cross-label state declared up-front (goto-safe).
        int k0, wb, trips, trips_rel, s_ji, seg_guard, kmv, kcv;
        unsigned long long jb;
        float u, v, nvs, wv, tt, denbF, rwin, rwin2, ywin, ywin2;
        bool negj;

        // Packed walk state: lo lanes = (umin,vmin); hi lanes = (-umax,-vmax).
        k0 = 0; seg_guard = 4096; jb = 0;
        ywin  = x[lane];                 // window: ywin[lane i] = x[wb + i]
        ywin2 = x[56 + lane];
        nvs = RLF(ywin, 0);              // x[0]
        v = fmaf(sgn, nvs, vnlam);       // lo: y0-lam ; hi: -(y0+lam)
        u = lam;
        kmv = 0; kcv = 1;

// absorb one element: SY = uniform y (raw, sign applied here), SR = 1/den
#define TVSTEP(SY, SR) { \
            const float u_t = fmaf(sgn, (SY), u) - v; \
            jb = __ballot(u_t < nlam);   /* lo: umin_t<-lam, hi: umax_t>lam */ \
            if (jb) goto midjump; \
            kmv = (u_t >= lam) ? kcv : kmv;  /* v_cmp + v_cndmask */ \
            kcv += 1; \
            const float u_n = fminf(u_t, lam); \
            v = fmaf(u_t - u_n, (SR), v);    /* both clamp corrections */ \
            u = u_n; }

// rotate windows forward by 56 elements (uniform)
#define TVSLIDE() { \
            ywin = ywin2; \
            wb += 56; \
            ywin2 = x[wb + 56 + lane]; \
            s_ji -= 56; trips_rel -= 56; \
            rwin = rwin2; \
            rwin2 = __builtin_amdgcn_rcpf(laneF + denbF); \
            denbF += 56.0f; }

seg_start:
        if (--seg_guard < 0) goto done;      // safety; k0 strictly increases
        trips = (TVW - 1) - k0;
        trips_rel = trips;
        wb = k0;
        s_ji = 1;                            // element k0+d at ywin idx d-56s
        denbF = 113.0f;                      // den base for slide s=2
        rwin = rw0c; rwin2 = rw1c;
        if (trips >= 8) {
            // ---- peel d=1..8: constant-lane readlanes, exact literal rn ----
            TVSTEP(RLF(ywin, 1), 0.5f)
            TVSTEP(RLF(ywin, 2), (1.0f / 3.0f))
            TVSTEP(RLF(ywin, 3), 0.25f)
            TVSTEP(RLF(ywin, 4), 0.2f)
            TVSTEP(RLF(ywin, 5), (1.0f / 6.0f))
            TVSTEP(RLF(ywin, 6), (1.0f / 7.0f))
            TVSTEP(RLF(ywin, 7), 0.125f)
            TVSTEP(RLF(ywin, 8), (1.0f / 9.0f))
            s_ji = 9;
            // ---- steady 8-step groups, window-fed ----
            for (;;) {
                if (s_ji + 7 > trips_rel) break;
                if (s_ji > 56) TVSLIDE()
                {
                    const int j0 = s_ji,     j1 = s_ji + 1, j2 = s_ji + 2, j3 = s_ji + 3,
                              j4 = s_ji + 4, j5 = s_ji + 5, j6 = s_ji + 6, j7 = s_ji + 7;
                    const float y0 = RLF(ywin, j0), y1 = RLF(ywin, j1),
                                y2 = RLF(ywin, j2), y3 = RLF(ywin, j3),
                                y4 = RLF(ywin, j4), y5 = RLF(ywin, j5),
                                y6 = RLF(ywin, j6), y7 = RLF(ywin, j7);
                    const float r0 = RLF(rwin, j0), r1 = RLF(rwin, j1),
                                r2 = RLF(rwin, j2), r3 = RLF(rwin, j3),
                                r4 = RLF(rwin, j4), r5 = RLF(rwin, j5),
                                r6 = RLF(rwin, j6), r7 = RLF(rwin, j7);
                    TVSTEP(y0, r0) TVSTEP(y1, r1) TVSTEP(y2, r2) TVSTEP(y3, r3)
                    TVSTEP(y4, r4) TVSTEP(y5, r5) TVSTEP(y6, r6) TVSTEP(y7, r7)
                }
                s_ji += 8;
            }
        }
        // ---- singles remainder (<=7, or whole segment when trips<8) ----
        while (s_ji <= trips_rel) {
            if (s_ji > 63) TVSLIDE()
            TVSTEP(RLF(ywin, s_ji), RLF(rwin, s_ji))
            s_ji += 1;
        }

        // ---- boundary: k == W-1, den = trips+1 ----
        {
            const unsigned long long bb = __ballot(u < 0.0f); // lo: umin<0, hi: umax>0
            if ((unsigned)bb) {              // flush [k0..km] at vmin; keep vmax/kp
                const int fe = __builtin_amdgcn_readlane(kmv, 0);   // km
                const int k0n = fe + 1;
                wv = v;                      // lo lanes hold vmin natively
                if (k0n < TVW) {             // window reload issued before stores
                    ywin  = x[k0n + lane];
                    ywin2 = x[k0n + 56 + lane];
                }
                { const int pe = fe < TVW - 1 ? fe : TVW - 1;
                  if (!hi) for (int p = k0 + l32; p <= pe; p += 32) x[p] = wv; }
                if (k0n >= TVW) goto done;
                nvs = RLF(ywin, 0);          // x[k0n]
                tt = fmaf(sgn, nvs, vnlam);  // hi: -x[k0n]-lam (lo value unused)
                u = hi ? (tt - v) : lam;     // uses OLD v (V_old)
                v = hi ? v : nvs;
                kmv = hi ? kmv : k0n;        // reset km (lo) only; kp kept
                kcv = k0n + 1;
                k0 = k0n;
                goto seg_start;
            } else if ((unsigned)(bb >> 32)) { // flush [k0..kp] at vmax; keep vmin/km
                const int fe = __builtin_amdgcn_readlane(kmv, 32);  // kp
                const int k0n = fe + 1;
                wv = -v;                     // hi lanes hold -vmax natively
                if (k0n < TVW) {
                    ywin  = x[k0n + lane];
                    ywin2 = x[k0n + 56 + lane];
                }
                { const int pe = fe < TVW - 1 ? fe : TVW - 1;
                  if (hi) for (int p = k0 + l32; p <= pe; p += 32) x[p] = wv; }
                if (k0n >= TVW) goto done;
                nvs = RLF(ywin, 0);
                tt = nvs + vnlam;            // lo: x[k0n]-lam (hi value unused)
                u = hi ? lam : (tt - v);     // uses OLD v (vmin)
                v = hi ? (-nvs) : v;
                kmv = hi ? k0n : kmv;        // reset kp (hi) only; km kept
                kcv = k0n + 1;
                k0 = k0n;
                goto seg_start;
            } else {                         // terminate: flush tail at mean value
                const float vt = fmaf(u, __builtin_amdgcn_rcpf((float)(trips + 1)), v);
                if (!hi) for (int p = k0 + l32; p < TVW; p += 32) x[p] = vt;
                goto done;
            }
        }

midjump: // jump while absorbing; jb lo bits = negative (priority), hi = positive
        {
            negj = (unsigned)jb != 0;
            const int fe = __builtin_amdgcn_readlane(kmv, negj ? 0 : 32); // km or kp
            const int k0n = fe + 1;          // fe <= W-2 here
            wv = hi ? -v : v;                // value this half would write
            ywin  = x[k0n + lane];           // reload issued before the stores
            ywin2 = x[k0n + 56 + lane];
            {
                const int p0 = k0 + l32;
                if ((negj != hi) && (p0 <= fe)) x[p0] = wv;   // common case: 1 store
                if (fe - k0 >= 32) {                          // rare long segment
                    if (negj != hi)
                        for (int p = p0 + 32; p <= fe; p += 32) x[p] = wv;
                }
            }
            nvs = RLF(ywin, 0);              // x[k0n]
            v = fmaf(sgn, nvs, negj ? vmcn : vmcp);  // v12 restart algebra, sign-folded
            u = lam;
            kmv = k0n; kcv = k0n + 1;
            k0 = k0n;
            goto seg_start;
        }
#undef TVSTEP
#undef TVSLIDE
done:   ;
        // ---- per-wave coalesced float4 writeback LDS -> out ----
        {
            const float4* b4 = (const float4*)(buf + wave * TVW);
            float4* d4 = (float4*)(out + (size_t)row * TVW);
            #pragma unroll
            for (int i = 0; i < TVW / 4; i += 64)
                d4[i + lane] = b4[i + lane];
        }
    }
#undef RLF
}

extern "C" void kernel_launch(void* const* d_in, const int* in_sizes, int n_in,
                              void* d_out, int out_size, void* d_ws, size_t ws_size,
                              hipStream_t stream) {
    const float* y    = (const float*)d_in[0];
    const float* lmbd = (const float*)d_in[1];
    float* out = (float*)d_out;

    const int total_rows = in_sizes[0] / TVW;              // 6144
    const int grid = (total_rows + WPB - 1) / WPB;         // 3072 blocks
    tv1d_condat_wave_kernel<<<grid, BLOCK, 0, stream>>>(y, lmbd, out, total_rows);
}